// Round 1
// baseline (1071.143 us; speedup 1.0000x reference)
//
#include <hip/hip_runtime.h>
#include <math.h>

#define B_   64
#define T_   500
#define IN_  1024
#define G_   8
#define HG_  128
#define J3_  384   // 3*HG

// ---------------------------------------------------------------------------
// Kernel A: input projection GEMM (fp32 vector, 8x8 register micro-tile)
//   xp[(tau*64 + b)*G + g][j] = sum_i x[b, t0+tau, g*128+i] * W_ih[g][j][i] + b_ih[g][j]
// tile: 128 rows (tau,b) x 128 cols (j), K=128 in 4 chunks of 32.
// LDS tiles XOR-swizzled at float4 granularity: granule = k4 ^ (r&7).
// ---------------------------------------------------------------------------
__global__ __launch_bounds__(256, 3)
void gru_xproj(const float* __restrict__ x, const float* __restrict__ Wih,
               const float* __restrict__ bih, float* __restrict__ xp,
               int t0)
{
    __shared__ float xs[128 * 32];
    __shared__ float wsm[128 * 32];

    const int tid = threadIdx.x;
    const int tx = tid & 15;        // j micro index
    const int ty = tid >> 4;        // row micro index
    const int g  = blockIdx.z;
    const int j0 = blockIdx.y * 128;
    const int row0 = blockIdx.x * 128;   // row id = tau*64 + b (within chunk)

    float acc[8][8];
#pragma unroll
    for (int m = 0; m < 8; ++m)
#pragma unroll
        for (int n = 0; n < 8; ++n) acc[m][n] = 0.f;

    for (int kc = 0; kc < 4; ++kc) {
        __syncthreads();   // protect previous iteration's LDS reads
#pragma unroll
        for (int q = 0; q < 4; ++q) {
            const int f  = tid + 256 * q;   // 0..1023
            const int r  = f >> 3;
            const int k4 = f & 7;
            const int rowid = row0 + r;
            const int b   = rowid & 63;
            const int tau = rowid >> 6;
            const float4 xv = *(const float4*)(x + (size_t)(b * T_ + t0 + tau) * IN_
                                                 + g * HG_ + kc * 32 + k4 * 4);
            *(float4*)(xs + r * 32 + ((k4 ^ (r & 7)) << 2)) = xv;
            const float4 wv = *(const float4*)(Wih + (size_t)(g * J3_ + j0 + r) * HG_
                                                   + kc * 32 + k4 * 4);
            *(float4*)(wsm + r * 32 + ((k4 ^ (r & 7)) << 2)) = wv;
        }
        __syncthreads();

#pragma unroll
        for (int k4 = 0; k4 < 8; ++k4) {
            float4 xv[8], wv[8];
#pragma unroll
            for (int m = 0; m < 8; ++m) {
                const int r = ty + 16 * m;
                xv[m] = *(const float4*)(xs + r * 32 + ((k4 ^ (r & 7)) << 2));
            }
#pragma unroll
            for (int n = 0; n < 8; ++n) {
                const int r = tx + 16 * n;
                wv[n] = *(const float4*)(wsm + r * 32 + ((k4 ^ (r & 7)) << 2));
            }
#pragma unroll
            for (int m = 0; m < 8; ++m)
#pragma unroll
                for (int n = 0; n < 8; ++n) {
                    acc[m][n] += xv[m].x * wv[n].x;
                    acc[m][n] += xv[m].y * wv[n].y;
                    acc[m][n] += xv[m].z * wv[n].z;
                    acc[m][n] += xv[m].w * wv[n].w;
                }
        }
    }

#pragma unroll
    for (int m = 0; m < 8; ++m) {
        const int rowid = row0 + ty + 16 * m;
        float* dst = xp + ((size_t)rowid * G_ + g) * J3_ + j0;
#pragma unroll
        for (int n = 0; n < 8; ++n) {
            const int j = tx + 16 * n;
            dst[j] = acc[m][n] + bih[g * J3_ + j0 + j];
        }
    }
}

// ---------------------------------------------------------------------------
// Kernel B: recurrence. One workgroup (512 threads) per (b,g) sequence.
// Thread (c = tid>>7, jq = tid&127) holds W_hh[g][p*128+jq][c*32 .. c*32+31]
// in registers (3 gates x 32 = 96 VGPR). h lives in LDS (128 floats).
// Per step: partial dots -> LDS reduce -> gates by c==0 threads.
// ---------------------------------------------------------------------------
__global__ __launch_bounds__(512, 4)
void gru_rec(const float* __restrict__ Whh, const float* __restrict__ bhh,
             const float* __restrict__ xp, float* __restrict__ out,
             float* __restrict__ hstate, int t0, int tc)
{
    const int tid = threadIdx.x;
    const int c   = tid >> 7;       // i-chunk 0..3 (wave-uniform)
    const int jq  = tid & 127;
    const int blk = blockIdx.x;     // 0..511
    const int b   = blk >> 3;
    const int g   = blk & 7;

    __shared__ float h_lds[HG_];
    __shared__ float part[12 * 128];   // [c][p][jq]

    // --- weights into registers ---
    float w0[32], w1[32], w2[32];
    {
        const float* wr0 = Whh + (size_t)(g * J3_ +   0 + jq) * HG_ + c * 32;
        const float* wr1 = Whh + (size_t)(g * J3_ + 128 + jq) * HG_ + c * 32;
        const float* wr2 = Whh + (size_t)(g * J3_ + 256 + jq) * HG_ + c * 32;
#pragma unroll
        for (int i4 = 0; i4 < 8; ++i4) {
            float4 v0 = *(const float4*)(wr0 + i4 * 4);
            float4 v1 = *(const float4*)(wr1 + i4 * 4);
            float4 v2 = *(const float4*)(wr2 + i4 * 4);
            w0[i4*4+0]=v0.x; w0[i4*4+1]=v0.y; w0[i4*4+2]=v0.z; w0[i4*4+3]=v0.w;
            w1[i4*4+0]=v1.x; w1[i4*4+1]=v1.y; w1[i4*4+2]=v1.z; w1[i4*4+3]=v1.w;
            w2[i4*4+0]=v2.x; w2[i4*4+1]=v2.y; w2[i4*4+2]=v2.z; w2[i4*4+3]=v2.w;
        }
    }

    float hreg = 0.f, bias0 = 0.f, bias1 = 0.f, bias2 = 0.f;
    if (c == 0) {
        bias0 = bhh[g * J3_ +       jq];
        bias1 = bhh[g * J3_ + 128 + jq];
        bias2 = bhh[g * J3_ + 256 + jq];
        hreg  = (t0 == 0) ? 0.f : hstate[(b * G_ + g) * HG_ + jq];
        h_lds[jq] = hreg;
    }
    __syncthreads();

    const float*  xpb     = xp + ((size_t)b * G_ + g) * J3_;   // + tau*B*G*384
    const size_t  tstride = (size_t)B_ * G_ * J3_;

    for (int tau = 0; tau < tc; ++tau) {
        float xr = 0.f, xz = 0.f, xn = 0.f;
        if (c == 0) {   // issue early; consumed after the FMA block
            const float* xpt = xpb + (size_t)tau * tstride;
            xr = xpt[jq]; xz = xpt[128 + jq]; xn = xpt[256 + jq];
        }

        float a0 = 0.f, a1 = 0.f, a2 = 0.f;
#pragma unroll
        for (int i4 = 0; i4 < 8; ++i4) {
            const float4 hv = *(const float4*)(h_lds + c * 32 + i4 * 4);
            a0 += w0[i4*4+0]*hv.x; a0 += w0[i4*4+1]*hv.y; a0 += w0[i4*4+2]*hv.z; a0 += w0[i4*4+3]*hv.w;
            a1 += w1[i4*4+0]*hv.x; a1 += w1[i4*4+1]*hv.y; a1 += w1[i4*4+2]*hv.z; a1 += w1[i4*4+3]*hv.w;
            a2 += w2[i4*4+0]*hv.x; a2 += w2[i4*4+1]*hv.y; a2 += w2[i4*4+2]*hv.z; a2 += w2[i4*4+3]*hv.w;
        }
        part[(c * 3 + 0) * 128 + jq] = a0;
        part[(c * 3 + 1) * 128 + jq] = a1;
        part[(c * 3 + 2) * 128 + jq] = a2;
        __syncthreads();

        if (c == 0) {
            float hr = bias0, hz = bias1, hn = bias2;
#pragma unroll
            for (int cc = 0; cc < 4; ++cc) {
                hr += part[(cc * 3 + 0) * 128 + jq];
                hz += part[(cc * 3 + 1) * 128 + jq];
                hn += part[(cc * 3 + 2) * 128 + jq];
            }
            const float r = 1.f / (1.f + __expf(-(xr + hr)));
            const float z = 1.f / (1.f + __expf(-(xz + hz)));
            const float pre = xn + r * hn;
            const float e2  = __expf(-2.f * fabsf(pre));
            float th = (1.f - e2) / (1.f + e2);
            th = copysignf(th, pre);
            const float hnew = (1.f - z) * th + z * hreg;
            hreg = hnew;
            h_lds[jq] = hnew;
            out[((size_t)b * T_ + (t0 + tau)) * IN_ + g * HG_ + jq] = hnew;
        }
        __syncthreads();
    }

    if (c == 0) hstate[(b * G_ + g) * HG_ + jq] = hreg;
}

// ---------------------------------------------------------------------------
extern "C" void kernel_launch(void* const* d_in, const int* in_sizes, int n_in,
                              void* d_out, int out_size, void* d_ws, size_t ws_size,
                              hipStream_t stream) {
    (void)in_sizes; (void)n_in; (void)out_size;
    const float* x   = (const float*)d_in[0];
    const float* Wih = (const float*)d_in[1];
    const float* Whh = (const float*)d_in[2];
    const float* bih = (const float*)d_in[3];
    const float* bhh = (const float*)d_in[4];
    float* out = (float*)d_out;

    // ws layout: [h-state: B*G*128 floats = 256KB][xp chunk buffer]
    const size_t hBytes = (size_t)B_ * G_ * HG_ * sizeof(float);   // 262144
    float* hstate = (float*)d_ws;
    float* xpbuf  = (float*)((char*)d_ws + hBytes);

    const size_t perT  = (size_t)B_ * G_ * J3_ * sizeof(float);    // 786432 B per timestep
    const size_t avail = (ws_size > hBytes) ? (ws_size - hBytes) : 0;

    // even divisors of 500, largest chunk that fits in ws
    const int cands[8] = {500, 250, 100, 50, 20, 10, 4, 2};
    int tc = 2;
    for (int i = 0; i < 8; ++i) {
        if ((size_t)cands[i] * perT <= avail) { tc = cands[i]; break; }
    }

    for (int t0 = 0; t0 < T_; t0 += tc) {
        dim3 gA(tc * 64 / 128, J3_ / 128, G_);   // (tc/2, 3, 8)
        gru_xproj<<<gA, 256, 0, stream>>>(x, Wih, bih, xpbuf, t0);
        gru_rec<<<512, 512, 0, stream>>>(Whh, bhh, xpbuf, out, hstate, t0, tc);
    }
}